// Round 8
// baseline (1107.736 us; speedup 1.0000x reference)
//
#include <hip/hip_runtime.h>

#define N_NODES 100000
#define E_EDGES 1600000
#define F_IN    128
#define H_DIM   64
#define C_OUT   16
#define L_LAYERS 3
#define NTOT    (E_EDGES + N_NODES)
#define MAXD    512   // LDS-staged degree cap in agg; fallback recomputes

#define BKN2    512                                   // nodes per bucket
#define NB2     ((N_NODES + BKN2 - 1) / BKN2)         // 196
#define BCAP    9216                                  // per-bucket capacity
#define CH      8192                                  // edges per scatter block
#define PB      ((E_EDGES + CH - 1) / CH)             // 196

// ---------------- edge-index dtype detection ----------------
__global__ void detect64_kernel(const unsigned int* __restrict__ e, int* flag) {
    __shared__ int s_any;
    if (threadIdx.x == 0) s_any = 0;
    __syncthreads();
    int any = 0;
    for (int i = threadIdx.x; i < 2048; i += 256)
        if (e[2 * i + 1] != 0u) any = 1;
    if (any) atomicOr(&s_any, 1);
    __syncthreads();
    if (threadIdx.x == 0) *flag = s_any ? 0 : 1;
}

// ---------------- pass B: block-local bucket sort + dense scatter ----------------
__global__ __launch_bounds__(256) void bucket_scatter2(
        const void* __restrict__ eidx, const int* __restrict__ flag,
        int* __restrict__ bcur, unsigned int* __restrict__ packed) {
    __shared__ int cnt[NB2], basel[NB2], curl[NB2], gbase[NB2];
    __shared__ int sd[256];
    __shared__ unsigned int stage[CH];
    __shared__ unsigned char bkt[CH];
    int t = threadIdx.x;
    int b0 = blockIdx.x * CH;
    int ne = min(CH, E_EDGES - b0);
    for (int i = t; i < NB2; i += 256) cnt[i] = 0;
    __syncthreads();

    int f64 = *flag;
    int es[CH / 256], ed[CH / 256];
    #pragma unroll
    for (int j = 0; j < CH / 256; ++j) {
        int idx = b0 + j * 256 + t;
        if (idx < E_EDGES) {
            if (f64) {
                es[j] = (int)((const long long*)eidx)[idx];
                ed[j] = (int)((const long long*)eidx)[E_EDGES + idx];
            } else {
                es[j] = ((const int*)eidx)[idx];
                ed[j] = ((const int*)eidx)[E_EDGES + idx];
            }
            atomicAdd(&cnt[ed[j] >> 9], 1);
        } else { es[j] = -1; }
    }
    __syncthreads();
    int v = (t < NB2) ? cnt[t] : 0;
    sd[t] = v;
    __syncthreads();
    for (int off = 1; off < 256; off <<= 1) {
        int u = (t >= off) ? sd[t - off] : 0;
        __syncthreads();
        sd[t] += u;
        __syncthreads();
    }
    if (t < NB2) {
        basel[t] = sd[t] - v;
        curl[t] = 0;
        gbase[t] = atomicAdd(&bcur[t], v);
    }
    __syncthreads();
    #pragma unroll
    for (int j = 0; j < CH / 256; ++j) {
        if (es[j] >= 0) {
            int b = ed[j] >> 9;
            int r = atomicAdd(&curl[b], 1);
            int pos = basel[b] + r;
            stage[pos] = ((unsigned)(ed[j] & (BKN2 - 1)) << 17) | (unsigned)es[j];
            bkt[pos] = (unsigned char)b;
        }
    }
    __syncthreads();
    for (int i = t; i < ne; i += 256) {
        int b = bkt[i];
        packed[(size_t)b * BCAP + gbase[b] + (i - basel[b])] = stage[i];
    }
}

// ---------------- pass B2: exclusive scan of final bucket counts ----------------
__global__ __launch_bounds__(256) void bucket_scan2(
        const int* __restrict__ bcur, int* __restrict__ ebase) {
    __shared__ int sd[256];
    int t = threadIdx.x;
    int v = (t < NB2) ? bcur[t] : 0;
    sd[t] = v;
    __syncthreads();
    for (int off = 1; off < 256; off <<= 1) {
        int u = (t >= off) ? sd[t - off] : 0;
        __syncthreads();
        sd[t] += u;
        __syncthreads();
    }
    if (t < NB2) ebase[t] = sd[t] - v;
}

// ---------------- pass C: per-bucket CSR finalize ----------------
__global__ __launch_bounds__(256) void csr_build2(
        const unsigned int* __restrict__ packed, const int* __restrict__ bcur,
        const int* __restrict__ ebase,
        int* __restrict__ row_ptr, int* __restrict__ csr_src) {
    __shared__ int cnt[BKN2], scn[BKN2], cur[BKN2];
    int b = blockIdx.x, t = threadIdx.x;
    int nbase = b * BKN2;
    int nn = min(BKN2, N_NODES - nbase);
    int ec = bcur[b];
    size_t pbase = (size_t)b * BCAP;
    int cbase = ebase[b] + nbase;
    cnt[t] = (t < nn) ? 1 : 0;
    cnt[t + 256] = (t + 256 < nn) ? 1 : 0;
    __syncthreads();
    for (int i = t; i < ec; i += 256)
        atomicAdd(&cnt[packed[pbase + i] >> 17], 1);
    __syncthreads();
    scn[t] = cnt[t];
    scn[t + 256] = cnt[t + 256];
    __syncthreads();
    for (int off = 1; off < BKN2; off <<= 1) {
        int u0 = (t >= off) ? scn[t - off] : 0;
        int u1 = (t + 256 >= off) ? scn[t + 256 - off] : 0;
        __syncthreads();
        scn[t] += u0;
        scn[t + 256] += u1;
        __syncthreads();
    }
    #pragma unroll
    for (int q = 0; q < 2; ++q) {
        int idx = t + q * 256;
        if (idx < nn) {
            int offi = scn[idx] - cnt[idx];
            row_ptr[nbase + idx] = cbase + offi;
            csr_src[cbase + offi] = nbase + idx;   // self-loop first
            cur[idx] = offi + 1;
        }
    }
    if (b == NB2 - 1 && t == 0) row_ptr[N_NODES] = cbase + ec + nn;
    __syncthreads();
    for (int i = t; i < ec; i += 256) {
        unsigned p = packed[pbase + i];
        int dl = p >> 17, s = (int)(p & 0x1FFFFu);
        int pos = atomicAdd(&cur[dl], 1);
        csr_src[cbase + pos] = s;
    }
}

// ---------------- LDS-staged coalesced GEMM ----------------
// C[N x 64] = A[N x K] @ W[K x 64]; 32 rows/block, 256 threads,
// 2 rows x 4 cols per thread. All global loads are lane-distinct contiguous
// float4 (coalesced); compute reads LDS (broadcast free, sA padded +4 for
// bank-conflict-free 4-row access). 24.7 KB LDS -> 6 blocks/CU.
#define GBR 32
#define KC  64

template<int K, bool ACT, bool DOTS>
__global__ __launch_bounds__(256) void gemm_lds_kernel(
        const float* __restrict__ A, const float* __restrict__ W,
        const float* __restrict__ bias,
        const float* __restrict__ asrc, const float* __restrict__ adst,
        float* __restrict__ C, float* __restrict__ as_, float* __restrict__ ad_) {
    __shared__ __align__(16) float sW[KC * 64];          // 16 KB
    __shared__ __align__(16) float sA[GBR][KC + 4];      // 8.7 KB
    int t = threadIdx.x;
    int r0 = blockIdx.x * GBR;
    int wave = t >> 6, lane = t & 63;
    int tr = wave * 4 + (lane >> 4);     // 0..15; local rows tr, tr+16
    int c0 = (lane & 15) * 4;
    int wcol = lane & 15;

    float acc[2][4];
    #pragma unroll
    for (int i = 0; i < 2; ++i)
        #pragma unroll
        for (int j = 0; j < 4; ++j) acc[i][j] = 0.f;

    const float4* W4 = (const float4*)W;

    for (int kc = 0; kc < K; kc += KC) {
        if (kc) __syncthreads();   // protect LDS reuse across chunks
        // stage W chunk (rows kc..kc+KC): contiguous 16 KB, coalesced
        {
            float4* sW4 = (float4*)sW;
            #pragma unroll
            for (int i = t; i < KC * 16; i += 256) sW4[i] = W4[kc * 16 + i];
        }
        // stage A tile chunk: GBR rows x KC floats, coalesced float4
        #pragma unroll
        for (int it = 0; it < (GBR * KC / 4) / 256; ++it) {
            int idx = it * 256 + t;
            int r = idx / (KC / 4);
            int c4 = idx % (KC / 4);
            int gr = r0 + r;
            float4 v = make_float4(0.f, 0.f, 0.f, 0.f);
            if (gr < N_NODES) v = *(const float4*)&A[(size_t)gr * K + kc + c4 * 4];
            *(float4*)&sA[r][c4 * 4] = v;
        }
        __syncthreads();
        #pragma unroll
        for (int kk = 0; kk < KC; kk += 4) {
            float4 w0 = *(const float4*)&sW[(kk + 0) * 64 + c0];
            float4 w1 = *(const float4*)&sW[(kk + 1) * 64 + c0];
            float4 w2 = *(const float4*)&sW[(kk + 2) * 64 + c0];
            float4 w3 = *(const float4*)&sW[(kk + 3) * 64 + c0];
            #pragma unroll
            for (int i = 0; i < 2; ++i) {
                float4 a = *(const float4*)&sA[tr + 16 * i][kk];
                acc[i][0] += a.x * w0.x + a.y * w1.x + a.z * w2.x + a.w * w3.x;
                acc[i][1] += a.x * w0.y + a.y * w1.y + a.z * w2.y + a.w * w3.y;
                acc[i][2] += a.x * w0.z + a.y * w1.z + a.z * w2.z + a.w * w3.z;
                acc[i][3] += a.x * w0.w + a.y * w1.w + a.z * w2.w + a.w * w3.w;
            }
        }
    }

    float bs[4] = {0.f, 0.f, 0.f, 0.f};
    float av[4], dv[4];
    if (ACT) {
        #pragma unroll
        for (int j = 0; j < 4; ++j) bs[j] = bias[c0 + j];
    }
    if (DOTS) {
        #pragma unroll
        for (int j = 0; j < 4; ++j) { av[j] = asrc[c0 + j]; dv[j] = adst[c0 + j]; }
    }
    #pragma unroll
    for (int i = 0; i < 2; ++i) {
        int grow = r0 + tr + 16 * i;
        if (grow >= N_NODES) continue;
        float4 o;
        float* op = (float*)&o;
        #pragma unroll
        for (int j = 0; j < 4; ++j) {
            float v = acc[i][j];
            if (ACT) { v += bs[j]; v = v > 0.f ? v : 0.01f * v; }
            op[j] = v;
        }
        *(float4*)&C[(size_t)grow * 64 + c0] = o;
        if (DOTS) {
            float ds = acc[i][0] * av[0] + acc[i][1] * av[1] + acc[i][2] * av[2] + acc[i][3] * av[3];
            float dd = acc[i][0] * dv[0] + acc[i][1] * dv[1] + acc[i][2] * dv[2] + acc[i][3] * dv[3];
            #pragma unroll
            for (int off = 1; off < 16; off <<= 1) {
                ds += __shfl_xor(ds, off);
                dd += __shfl_xor(dd, off);
            }
            if ((lane & 15) == 0) { as_[grow] = ds; ad_[grow] = dd; }
        }
    }
}

// ---------------- fused aggregation: softmax + weighted gather + bias + act ----
__global__ __launch_bounds__(256) void agg_kernel(
        const int* __restrict__ row_ptr, const int* __restrict__ csr_src,
        const float* __restrict__ as_, const float* __restrict__ ad_,
        const float* __restrict__ hw, const float* __restrict__ bc,
        float* __restrict__ hout) {
    __shared__ float exbuf[4][MAXD];
    __shared__ int   sbuf[4][MAXD];
    int wave = threadIdx.x >> 6, lane = threadIdx.x & 63;
    int node = blockIdx.x * 4 + wave;
    if (node >= N_NODES) return;
    int rs = row_ptr[node], re = row_ptr[node + 1];
    int deg = re - rs;
    float aD = ad_[node];
    float psum = 0.f;
    for (int i = lane; i < deg; i += 64) {
        int s = csr_src[rs + i];
        float v = as_[s] + aD;
        v = v > 0.f ? v : 0.2f * v;
        float p = __expf(v);
        if (deg <= MAXD) { exbuf[wave][i] = p; sbuf[wave][i] = s; }
        psum += p;
    }
    #pragma unroll
    for (int off = 32; off >= 1; off >>= 1) psum += __shfl_xor(psum, off);
    float inv = 1.f / (psum + 1e-16f);
    float acc = 0.f;
    if (deg <= MAXD) {
        int i = 0;
        for (; i + 4 <= deg; i += 4) {
            int s0 = sbuf[wave][i],     s1 = sbuf[wave][i + 1];
            int s2 = sbuf[wave][i + 2], s3 = sbuf[wave][i + 3];
            float w0 = exbuf[wave][i]     * inv, w1 = exbuf[wave][i + 1] * inv;
            float w2 = exbuf[wave][i + 2] * inv, w3 = exbuf[wave][i + 3] * inv;
            acc += w0 * hw[(size_t)s0 * H_DIM + lane];
            acc += w1 * hw[(size_t)s1 * H_DIM + lane];
            acc += w2 * hw[(size_t)s2 * H_DIM + lane];
            acc += w3 * hw[(size_t)s3 * H_DIM + lane];
        }
        for (; i < deg; ++i)
            acc += exbuf[wave][i] * inv * hw[(size_t)sbuf[wave][i] * H_DIM + lane];
    } else {
        for (int i = 0; i < deg; ++i) {
            int s = csr_src[rs + i];
            float v = as_[s] + aD;
            v = v > 0.f ? v : 0.2f * v;
            acc += __expf(v) * inv * hw[(size_t)s * H_DIM + lane];
        }
    }
    float v = acc + bc[lane];
    hout[(size_t)node * H_DIM + lane] = v > 0.f ? v : 0.01f * v;
}

// ---------------- output GEMM + log_softmax ----------------
__global__ __launch_bounds__(256) void out_logsoftmax_kernel(
        const float* __restrict__ h, const float* __restrict__ W,
        const float* __restrict__ b, float* __restrict__ out) {
    __shared__ float sW[H_DIM * C_OUT];
    __shared__ float sh[16][H_DIM];
    __shared__ float sb[C_OUT];
    int t = threadIdx.x;
    for (int i = t; i < H_DIM * C_OUT; i += 256) sW[i] = W[i];
    if (t < C_OUT) sb[t] = b[t];
    int row0 = blockIdx.x * 16;
    for (int i = t; i < 16 * H_DIM; i += 256) {
        int r = i >> 6, k = i & 63;
        sh[r][k] = h[(row0 + r) * H_DIM + k];
    }
    __syncthreads();
    int r = t >> 4, c = t & 15;
    float acc = sb[c];
    #pragma unroll
    for (int k = 0; k < H_DIM; ++k) acc += sh[r][k] * sW[k * C_OUT + c];
    float m = acc;
    #pragma unroll
    for (int off = 8; off >= 1; off >>= 1) m = fmaxf(m, __shfl_xor(m, off, 16));
    float e = __expf(acc - m);
    float ssum = e;
    #pragma unroll
    for (int off = 8; off >= 1; off >>= 1) ssum += __shfl_xor(ssum, off, 16);
    out[(row0 + r) * C_OUT + c] = acc - m - __logf(ssum);
}

extern "C" void kernel_launch(void* const* d_in, const int* in_sizes, int n_in,
                              void* d_out, int out_size, void* d_ws, size_t ws_size,
                              hipStream_t stream) {
    const float* x     = (const float*)d_in[0];
    const void*  eidx  = d_in[1];
    const float* W_in  = (const float*)d_in[3];
    const float* b_in  = (const float*)d_in[4];
    const float* Wc    = (const float*)d_in[5];
    const float* a_src = (const float*)d_in[6];
    const float* a_dst = (const float*)d_in[7];
    const float* bc    = (const float*)d_in[8];
    const float* W_out = (const float*)d_in[9];
    const float* b_out = (const float*)d_in[10];
    float* out = (float*)d_out;

    // workspace layout
    float* h        = (float*)d_ws;                        // N*64
    float* hw       = h  + (size_t)N_NODES * H_DIM;        // N*64
    float* as_      = hw + (size_t)N_NODES * H_DIM;        // N
    float* ad_      = as_ + N_NODES;                       // N
    int*   row_ptr  = (int*)(ad_ + N_NODES);               // N+1
    int*   csr_src  = row_ptr + N_NODES + 1;               // E+N
    unsigned int* packed = (unsigned int*)(csr_src + NTOT);// NB2*BCAP
    int*   bcur     = (int*)(packed + (size_t)NB2 * BCAP); // NB2
    int*   ebase    = bcur + NB2;                          // NB2
    int*   flag     = ebase + NB2;                         // 1

    detect64_kernel<<<1, 256, 0, stream>>>((const unsigned int*)eidx, flag);
    hipMemsetAsync(bcur, 0, NB2 * sizeof(int), stream);
    bucket_scatter2<<<PB, 256, 0, stream>>>(eidx, flag, bcur, packed);
    bucket_scan2<<<1, 256, 0, stream>>>(bcur, ebase);
    csr_build2<<<NB2, 256, 0, stream>>>(packed, bcur, ebase, row_ptr, csr_src);

    int gblocks = (N_NODES + GBR - 1) / GBR;
    gemm_lds_kernel<F_IN, true, false><<<gblocks, 256, 0, stream>>>(
        x, W_in, b_in, nullptr, nullptr, h, nullptr, nullptr);

    float* hin = h;
    float* hx  = hw;
    for (int l = 0; l < L_LAYERS; ++l) {
        gemm_lds_kernel<H_DIM, false, true><<<gblocks, 256, 0, stream>>>(
            hin, Wc + l * H_DIM * H_DIM, nullptr,
            a_src + l * H_DIM, a_dst + l * H_DIM, hx, as_, ad_);
        agg_kernel<<<(N_NODES + 3) / 4, 256, 0, stream>>>(
            row_ptr, csr_src, as_, ad_, hx, bc + l * H_DIM, hin);
    }

    out_logsoftmax_kernel<<<N_NODES / 16, 256, 0, stream>>>(hin, W_out, b_out, out);
}

// Round 9
// 387.215 us; speedup vs baseline: 2.8608x; 2.8608x over previous
//
#include <hip/hip_runtime.h>

#define N_NODES 100000
#define E_EDGES 1600000
#define F_IN    128
#define H_DIM   64
#define C_OUT   16
#define L_LAYERS 3
#define NTOT    (E_EDGES + N_NODES)
#define MAXD    512   // LDS-staged degree cap in agg; fallback recomputes

#define BKN2    512                                   // nodes per bucket
#define NB2     ((N_NODES + BKN2 - 1) / BKN2)         // 196
#define BCAP    9216                                  // per-bucket capacity
#define CH      8192                                  // edges per scatter block
#define PB      ((E_EDGES + CH - 1) / CH)             // 196

// ---------------- edge-index dtype detection ----------------
__global__ void detect64_kernel(const unsigned int* __restrict__ e, int* flag) {
    __shared__ int s_any;
    if (threadIdx.x == 0) s_any = 0;
    __syncthreads();
    int any = 0;
    for (int i = threadIdx.x; i < 2048; i += 256)
        if (e[2 * i + 1] != 0u) any = 1;
    if (any) atomicOr(&s_any, 1);
    __syncthreads();
    if (threadIdx.x == 0) *flag = s_any ? 0 : 1;
}

// ---------------- pass B: block-local bucket sort + dense scatter ----------------
__global__ __launch_bounds__(256) void bucket_scatter2(
        const void* __restrict__ eidx, const int* __restrict__ flag,
        int* __restrict__ bcur, unsigned int* __restrict__ packed) {
    __shared__ int cnt[NB2], basel[NB2], curl[NB2], gbase[NB2];
    __shared__ int sd[256];
    __shared__ unsigned int stage[CH];
    __shared__ unsigned char bkt[CH];
    int t = threadIdx.x;
    int b0 = blockIdx.x * CH;
    int ne = min(CH, E_EDGES - b0);
    for (int i = t; i < NB2; i += 256) cnt[i] = 0;
    __syncthreads();

    int f64 = *flag;
    int es[CH / 256], ed[CH / 256];
    #pragma unroll
    for (int j = 0; j < CH / 256; ++j) {
        int idx = b0 + j * 256 + t;
        if (idx < E_EDGES) {
            if (f64) {
                es[j] = (int)((const long long*)eidx)[idx];
                ed[j] = (int)((const long long*)eidx)[E_EDGES + idx];
            } else {
                es[j] = ((const int*)eidx)[idx];
                ed[j] = ((const int*)eidx)[E_EDGES + idx];
            }
            atomicAdd(&cnt[ed[j] >> 9], 1);
        } else { es[j] = -1; }
    }
    __syncthreads();
    int v = (t < NB2) ? cnt[t] : 0;
    sd[t] = v;
    __syncthreads();
    for (int off = 1; off < 256; off <<= 1) {
        int u = (t >= off) ? sd[t - off] : 0;
        __syncthreads();
        sd[t] += u;
        __syncthreads();
    }
    if (t < NB2) {
        basel[t] = sd[t] - v;
        curl[t] = 0;
        gbase[t] = atomicAdd(&bcur[t], v);
    }
    __syncthreads();
    #pragma unroll
    for (int j = 0; j < CH / 256; ++j) {
        if (es[j] >= 0) {
            int b = ed[j] >> 9;
            int r = atomicAdd(&curl[b], 1);
            int pos = basel[b] + r;
            stage[pos] = ((unsigned)(ed[j] & (BKN2 - 1)) << 17) | (unsigned)es[j];
            bkt[pos] = (unsigned char)b;
        }
    }
    __syncthreads();
    for (int i = t; i < ne; i += 256) {
        int b = bkt[i];
        packed[(size_t)b * BCAP + gbase[b] + (i - basel[b])] = stage[i];
    }
}

// ---------------- pass B2: exclusive scan of final bucket counts ----------------
__global__ __launch_bounds__(256) void bucket_scan2(
        const int* __restrict__ bcur, int* __restrict__ ebase) {
    __shared__ int sd[256];
    int t = threadIdx.x;
    int v = (t < NB2) ? bcur[t] : 0;
    sd[t] = v;
    __syncthreads();
    for (int off = 1; off < 256; off <<= 1) {
        int u = (t >= off) ? sd[t - off] : 0;
        __syncthreads();
        sd[t] += u;
        __syncthreads();
    }
    if (t < NB2) ebase[t] = sd[t] - v;
}

// ---------------- pass C: per-bucket CSR finalize ----------------
__global__ __launch_bounds__(256) void csr_build2(
        const unsigned int* __restrict__ packed, const int* __restrict__ bcur,
        const int* __restrict__ ebase,
        int* __restrict__ row_ptr, int* __restrict__ csr_src) {
    __shared__ int cnt[BKN2], scn[BKN2], cur[BKN2];
    int b = blockIdx.x, t = threadIdx.x;
    int nbase = b * BKN2;
    int nn = min(BKN2, N_NODES - nbase);
    int ec = bcur[b];
    size_t pbase = (size_t)b * BCAP;
    int cbase = ebase[b] + nbase;
    cnt[t] = (t < nn) ? 1 : 0;
    cnt[t + 256] = (t + 256 < nn) ? 1 : 0;
    __syncthreads();
    for (int i = t; i < ec; i += 256)
        atomicAdd(&cnt[packed[pbase + i] >> 17], 1);
    __syncthreads();
    scn[t] = cnt[t];
    scn[t + 256] = cnt[t + 256];
    __syncthreads();
    for (int off = 1; off < BKN2; off <<= 1) {
        int u0 = (t >= off) ? scn[t - off] : 0;
        int u1 = (t + 256 >= off) ? scn[t + 256 - off] : 0;
        __syncthreads();
        scn[t] += u0;
        scn[t + 256] += u1;
        __syncthreads();
    }
    #pragma unroll
    for (int q = 0; q < 2; ++q) {
        int idx = t + q * 256;
        if (idx < nn) {
            int offi = scn[idx] - cnt[idx];
            row_ptr[nbase + idx] = cbase + offi;
            csr_src[cbase + offi] = nbase + idx;   // self-loop first
            cur[idx] = offi + 1;
        }
    }
    if (b == NB2 - 1 && t == 0) row_ptr[N_NODES] = cbase + ec + nn;
    __syncthreads();
    for (int i = t; i < ec; i += 256) {
        unsigned p = packed[pbase + i];
        int dl = p >> 17, s = (int)(p & 0x1FFFFu);
        int pos = atomicAdd(&cur[dl], 1);
        csr_src[cbase + pos] = s;
    }
}

// ---------------- LDS-staged coalesced GEMM, balanced tile ----------------
// C[N x 64] = A[N x K] @ W[K x 64]; 64 rows/block, 256 threads,
// 4 rows x 4 cols per thread (16 acc). Global loads all lane-distinct
// coalesced float4. Inner loop: 8 ds_read_b128 per 16 FMA-instr (balanced
// with per-CU LDS pipe). #pragma unroll 2 caps register pressure (R7 lesson:
// full unroll -> 256 VGPR spill -> 2.2 GB scratch traffic).
#define GBR 64
#define KC  64
#define SAP (KC + 4)

template<int K, bool ACT, bool DOTS>
__global__ __launch_bounds__(256) void gemm_lds_kernel(
        const float* __restrict__ A, const float* __restrict__ W,
        const float* __restrict__ bias,
        const float* __restrict__ asrc, const float* __restrict__ adst,
        float* __restrict__ C, float* __restrict__ as_, float* __restrict__ ad_) {
    __shared__ __align__(16) float sW[KC * 64];      // 16 KB
    __shared__ __align__(16) float sA[GBR][SAP];     // 17.4 KB
    int t = threadIdx.x;
    int r0 = blockIdx.x * GBR;
    int wave = t >> 6, lane = t & 63;
    int tr = wave * 4 + (lane >> 4);     // 0..15; local rows tr + 16*i, i=0..3
    int c0 = (lane & 15) * 4;

    float acc[4][4];
    #pragma unroll
    for (int i = 0; i < 4; ++i)
        #pragma unroll
        for (int j = 0; j < 4; ++j) acc[i][j] = 0.f;

    for (int kc = 0; kc < K; kc += KC) {
        if (kc) __syncthreads();
        // stage W chunk (rows kc..kc+KC): 16 KB contiguous, coalesced
        {
            const float4* W4 = (const float4*)(W + kc * 64);
            float4* sW4 = (float4*)sW;
            for (int i = t; i < KC * 16; i += 256) sW4[i] = W4[i];
        }
        // stage A tile: GBR rows x KC floats, coalesced float4 (lane-distinct)
        for (int it = 0; it < (GBR * KC / 4) / 256; ++it) {
            int idx = it * 256 + t;
            int r = idx >> 4;            // / (KC/4)
            int c4 = idx & 15;
            int gr = r0 + r;
            float4 v = make_float4(0.f, 0.f, 0.f, 0.f);
            if (gr < N_NODES) v = *(const float4*)&A[(size_t)gr * K + kc + c4 * 4];
            *(float4*)&sA[r][c4 * 4] = v;
        }
        __syncthreads();
        #pragma unroll 2
        for (int kk = 0; kk < KC; kk += 4) {
            float4 w0 = *(const float4*)&sW[(kk + 0) * 64 + c0];
            float4 w1 = *(const float4*)&sW[(kk + 1) * 64 + c0];
            float4 w2 = *(const float4*)&sW[(kk + 2) * 64 + c0];
            float4 w3 = *(const float4*)&sW[(kk + 3) * 64 + c0];
            #pragma unroll
            for (int i = 0; i < 4; ++i) {
                float4 a = *(const float4*)&sA[tr + 16 * i][kk];
                acc[i][0] += a.x * w0.x + a.y * w1.x + a.z * w2.x + a.w * w3.x;
                acc[i][1] += a.x * w0.y + a.y * w1.y + a.z * w2.y + a.w * w3.y;
                acc[i][2] += a.x * w0.z + a.y * w1.z + a.z * w2.z + a.w * w3.z;
                acc[i][3] += a.x * w0.w + a.y * w1.w + a.z * w2.w + a.w * w3.w;
            }
        }
    }

    float bs[4] = {0.f, 0.f, 0.f, 0.f};
    float av[4], dv[4];
    if (ACT) {
        #pragma unroll
        for (int j = 0; j < 4; ++j) bs[j] = bias[c0 + j];
    }
    if (DOTS) {
        #pragma unroll
        for (int j = 0; j < 4; ++j) { av[j] = asrc[c0 + j]; dv[j] = adst[c0 + j]; }
    }
    #pragma unroll
    for (int i = 0; i < 4; ++i) {
        int grow = r0 + tr + 16 * i;
        if (grow >= N_NODES) continue;
        float4 o;
        float* op = (float*)&o;
        #pragma unroll
        for (int j = 0; j < 4; ++j) {
            float v = acc[i][j];
            if (ACT) { v += bs[j]; v = v > 0.f ? v : 0.01f * v; }
            op[j] = v;
        }
        *(float4*)&C[(size_t)grow * 64 + c0] = o;
        if (DOTS) {
            float ds = acc[i][0] * av[0] + acc[i][1] * av[1] + acc[i][2] * av[2] + acc[i][3] * av[3];
            float dd = acc[i][0] * dv[0] + acc[i][1] * dv[1] + acc[i][2] * dv[2] + acc[i][3] * dv[3];
            #pragma unroll
            for (int off = 1; off < 16; off <<= 1) {
                ds += __shfl_xor(ds, off);
                dd += __shfl_xor(dd, off);
            }
            if ((lane & 15) == 0) { as_[grow] = ds; ad_[grow] = dd; }
        }
    }
}

// ---------------- fused aggregation: softmax + weighted gather + bias + act ----
__global__ __launch_bounds__(256) void agg_kernel(
        const int* __restrict__ row_ptr, const int* __restrict__ csr_src,
        const float* __restrict__ as_, const float* __restrict__ ad_,
        const float* __restrict__ hw, const float* __restrict__ bc,
        float* __restrict__ hout) {
    __shared__ float exbuf[4][MAXD];
    __shared__ int   sbuf[4][MAXD];
    int wave = threadIdx.x >> 6, lane = threadIdx.x & 63;
    int node = blockIdx.x * 4 + wave;
    if (node >= N_NODES) return;
    int rs = row_ptr[node], re = row_ptr[node + 1];
    int deg = re - rs;
    float aD = ad_[node];
    float psum = 0.f;
    for (int i = lane; i < deg; i += 64) {
        int s = csr_src[rs + i];
        float v = as_[s] + aD;
        v = v > 0.f ? v : 0.2f * v;
        float p = __expf(v);
        if (deg <= MAXD) { exbuf[wave][i] = p; sbuf[wave][i] = s; }
        psum += p;
    }
    #pragma unroll
    for (int off = 32; off >= 1; off >>= 1) psum += __shfl_xor(psum, off);
    float inv = 1.f / (psum + 1e-16f);
    float acc = 0.f;
    if (deg <= MAXD) {
        int i = 0;
        for (; i + 4 <= deg; i += 4) {
            int s0 = sbuf[wave][i],     s1 = sbuf[wave][i + 1];
            int s2 = sbuf[wave][i + 2], s3 = sbuf[wave][i + 3];
            float w0 = exbuf[wave][i]     * inv, w1 = exbuf[wave][i + 1] * inv;
            float w2 = exbuf[wave][i + 2] * inv, w3 = exbuf[wave][i + 3] * inv;
            acc += w0 * hw[(size_t)s0 * H_DIM + lane];
            acc += w1 * hw[(size_t)s1 * H_DIM + lane];
            acc += w2 * hw[(size_t)s2 * H_DIM + lane];
            acc += w3 * hw[(size_t)s3 * H_DIM + lane];
        }
        for (; i < deg; ++i)
            acc += exbuf[wave][i] * inv * hw[(size_t)sbuf[wave][i] * H_DIM + lane];
    } else {
        for (int i = 0; i < deg; ++i) {
            int s = csr_src[rs + i];
            float v = as_[s] + aD;
            v = v > 0.f ? v : 0.2f * v;
            acc += __expf(v) * inv * hw[(size_t)s * H_DIM + lane];
        }
    }
    float v = acc + bc[lane];
    hout[(size_t)node * H_DIM + lane] = v > 0.f ? v : 0.01f * v;
}

// ---------------- output GEMM + log_softmax ----------------
__global__ __launch_bounds__(256) void out_logsoftmax_kernel(
        const float* __restrict__ h, const float* __restrict__ W,
        const float* __restrict__ b, float* __restrict__ out) {
    __shared__ float sW[H_DIM * C_OUT];
    __shared__ float sh[16][H_DIM];
    __shared__ float sb[C_OUT];
    int t = threadIdx.x;
    for (int i = t; i < H_DIM * C_OUT; i += 256) sW[i] = W[i];
    if (t < C_OUT) sb[t] = b[t];
    int row0 = blockIdx.x * 16;
    for (int i = t; i < 16 * H_DIM; i += 256) {
        int r = i >> 6, k = i & 63;
        sh[r][k] = h[(row0 + r) * H_DIM + k];
    }
    __syncthreads();
    int r = t >> 4, c = t & 15;
    float acc = sb[c];
    #pragma unroll
    for (int k = 0; k < H_DIM; ++k) acc += sh[r][k] * sW[k * C_OUT + c];
    float m = acc;
    #pragma unroll
    for (int off = 8; off >= 1; off >>= 1) m = fmaxf(m, __shfl_xor(m, off, 16));
    float e = __expf(acc - m);
    float ssum = e;
    #pragma unroll
    for (int off = 8; off >= 1; off >>= 1) ssum += __shfl_xor(ssum, off, 16);
    out[(row0 + r) * C_OUT + c] = acc - m - __logf(ssum);
}

extern "C" void kernel_launch(void* const* d_in, const int* in_sizes, int n_in,
                              void* d_out, int out_size, void* d_ws, size_t ws_size,
                              hipStream_t stream) {
    const float* x     = (const float*)d_in[0];
    const void*  eidx  = d_in[1];
    const float* W_in  = (const float*)d_in[3];
    const float* b_in  = (const float*)d_in[4];
    const float* Wc    = (const float*)d_in[5];
    const float* a_src = (const float*)d_in[6];
    const float* a_dst = (const float*)d_in[7];
    const float* bc    = (const float*)d_in[8];
    const float* W_out = (const float*)d_in[9];
    const float* b_out = (const float*)d_in[10];
    float* out = (float*)d_out;

    // workspace layout
    float* h        = (float*)d_ws;                        // N*64
    float* hw       = h  + (size_t)N_NODES * H_DIM;        // N*64
    float* as_      = hw + (size_t)N_NODES * H_DIM;        // N
    float* ad_      = as_ + N_NODES;                       // N
    int*   row_ptr  = (int*)(ad_ + N_NODES);               // N+1
    int*   csr_src  = row_ptr + N_NODES + 1;               // E+N
    unsigned int* packed = (unsigned int*)(csr_src + NTOT);// NB2*BCAP
    int*   bcur     = (int*)(packed + (size_t)NB2 * BCAP); // NB2
    int*   ebase    = bcur + NB2;                          // NB2
    int*   flag     = ebase + NB2;                         // 1

    detect64_kernel<<<1, 256, 0, stream>>>((const unsigned int*)eidx, flag);
    hipMemsetAsync(bcur, 0, NB2 * sizeof(int), stream);
    bucket_scatter2<<<PB, 256, 0, stream>>>(eidx, flag, bcur, packed);
    bucket_scan2<<<1, 256, 0, stream>>>(bcur, ebase);
    csr_build2<<<NB2, 256, 0, stream>>>(packed, bcur, ebase, row_ptr, csr_src);

    int gblocks = (N_NODES + GBR - 1) / GBR;
    gemm_lds_kernel<F_IN, true, false><<<gblocks, 256, 0, stream>>>(
        x, W_in, b_in, nullptr, nullptr, h, nullptr, nullptr);

    float* hin = h;
    float* hx  = hw;
    for (int l = 0; l < L_LAYERS; ++l) {
        gemm_lds_kernel<H_DIM, false, true><<<gblocks, 256, 0, stream>>>(
            hin, Wc + l * H_DIM * H_DIM, nullptr,
            a_src + l * H_DIM, a_dst + l * H_DIM, hx, as_, ad_);
        agg_kernel<<<(N_NODES + 3) / 4, 256, 0, stream>>>(
            row_ptr, csr_src, as_, ad_, hx, bc + l * H_DIM, hin);
    }

    out_logsoftmax_kernel<<<N_NODES / 16, 256, 0, stream>>>(hin, W_out, b_out, out);
}

// Round 10
// 334.855 us; speedup vs baseline: 3.3081x; 1.1564x over previous
//
#include <hip/hip_runtime.h>

#define N_NODES 100000
#define E_EDGES 1600000
#define F_IN    128
#define H_DIM   64
#define C_OUT   16
#define L_LAYERS 3
#define NTOT    (E_EDGES + N_NODES)
#define MAXD    512   // LDS-staged degree cap in agg; fallback recomputes

#define BKN2    512                                   // nodes per bucket
#define NB2     ((N_NODES + BKN2 - 1) / BKN2)         // 196
#define BCAP    9216                                  // per-bucket capacity
#define CH      8192                                  // edges per scatter block
#define PB      ((E_EDGES + CH - 1) / CH)             // 196

// bf16 helpers (RNE)
__device__ inline unsigned short f2bf(float f) {
    unsigned u = __float_as_uint(f);
    return (unsigned short)((u + 0x7FFFu + ((u >> 16) & 1u)) >> 16);
}
__device__ inline float bf_lo(unsigned p) { return __uint_as_float(p << 16); }
__device__ inline float bf_hi(unsigned p) { return __uint_as_float(p & 0xFFFF0000u); }

// ---------------- edge-index dtype detection ----------------
__global__ void detect64_kernel(const unsigned int* __restrict__ e, int* flag) {
    __shared__ int s_any;
    if (threadIdx.x == 0) s_any = 0;
    __syncthreads();
    int any = 0;
    for (int i = threadIdx.x; i < 2048; i += 256)
        if (e[2 * i + 1] != 0u) any = 1;
    if (any) atomicOr(&s_any, 1);
    __syncthreads();
    if (threadIdx.x == 0) *flag = s_any ? 0 : 1;
}

// ---------------- pass B: block-local bucket sort + dense scatter ----------------
__global__ __launch_bounds__(256) void bucket_scatter2(
        const void* __restrict__ eidx, const int* __restrict__ flag,
        int* __restrict__ bcur, unsigned int* __restrict__ packed) {
    __shared__ int cnt[NB2], basel[NB2], curl[NB2], gbase[NB2];
    __shared__ int sd[256];
    __shared__ unsigned int stage[CH];
    __shared__ unsigned char bkt[CH];
    int t = threadIdx.x;
    int b0 = blockIdx.x * CH;
    int ne = min(CH, E_EDGES - b0);
    for (int i = t; i < NB2; i += 256) cnt[i] = 0;
    __syncthreads();

    int f64 = *flag;
    int es[CH / 256], ed[CH / 256];
    #pragma unroll
    for (int j = 0; j < CH / 256; ++j) {
        int idx = b0 + j * 256 + t;
        if (idx < E_EDGES) {
            if (f64) {
                es[j] = (int)((const long long*)eidx)[idx];
                ed[j] = (int)((const long long*)eidx)[E_EDGES + idx];
            } else {
                es[j] = ((const int*)eidx)[idx];
                ed[j] = ((const int*)eidx)[E_EDGES + idx];
            }
            atomicAdd(&cnt[ed[j] >> 9], 1);
        } else { es[j] = -1; }
    }
    __syncthreads();
    int v = (t < NB2) ? cnt[t] : 0;
    sd[t] = v;
    __syncthreads();
    for (int off = 1; off < 256; off <<= 1) {
        int u = (t >= off) ? sd[t - off] : 0;
        __syncthreads();
        sd[t] += u;
        __syncthreads();
    }
    if (t < NB2) {
        basel[t] = sd[t] - v;
        curl[t] = 0;
        gbase[t] = atomicAdd(&bcur[t], v);
    }
    __syncthreads();
    #pragma unroll
    for (int j = 0; j < CH / 256; ++j) {
        if (es[j] >= 0) {
            int b = ed[j] >> 9;
            int r = atomicAdd(&curl[b], 1);
            int pos = basel[b] + r;
            stage[pos] = ((unsigned)(ed[j] & (BKN2 - 1)) << 17) | (unsigned)es[j];
            bkt[pos] = (unsigned char)b;
        }
    }
    __syncthreads();
    for (int i = t; i < ne; i += 256) {
        int b = bkt[i];
        packed[(size_t)b * BCAP + gbase[b] + (i - basel[b])] = stage[i];
    }
}

// ---------------- pass B2: exclusive scan of final bucket counts ----------------
__global__ __launch_bounds__(256) void bucket_scan2(
        const int* __restrict__ bcur, int* __restrict__ ebase) {
    __shared__ int sd[256];
    int t = threadIdx.x;
    int v = (t < NB2) ? bcur[t] : 0;
    sd[t] = v;
    __syncthreads();
    for (int off = 1; off < 256; off <<= 1) {
        int u = (t >= off) ? sd[t - off] : 0;
        __syncthreads();
        sd[t] += u;
        __syncthreads();
    }
    if (t < NB2) ebase[t] = sd[t] - v;
}

// ---------------- pass C: per-bucket CSR finalize ----------------
__global__ __launch_bounds__(256) void csr_build2(
        const unsigned int* __restrict__ packed, const int* __restrict__ bcur,
        const int* __restrict__ ebase,
        int* __restrict__ row_ptr, int* __restrict__ csr_src) {
    __shared__ int cnt[BKN2], scn[BKN2], cur[BKN2];
    int b = blockIdx.x, t = threadIdx.x;
    int nbase = b * BKN2;
    int nn = min(BKN2, N_NODES - nbase);
    int ec = bcur[b];
    size_t pbase = (size_t)b * BCAP;
    int cbase = ebase[b] + nbase;
    cnt[t] = (t < nn) ? 1 : 0;
    cnt[t + 256] = (t + 256 < nn) ? 1 : 0;
    __syncthreads();
    for (int i = t; i < ec; i += 256)
        atomicAdd(&cnt[packed[pbase + i] >> 17], 1);
    __syncthreads();
    scn[t] = cnt[t];
    scn[t + 256] = cnt[t + 256];
    __syncthreads();
    for (int off = 1; off < BKN2; off <<= 1) {
        int u0 = (t >= off) ? scn[t - off] : 0;
        int u1 = (t + 256 >= off) ? scn[t + 256 - off] : 0;
        __syncthreads();
        scn[t] += u0;
        scn[t + 256] += u1;
        __syncthreads();
    }
    #pragma unroll
    for (int q = 0; q < 2; ++q) {
        int idx = t + q * 256;
        if (idx < nn) {
            int offi = scn[idx] - cnt[idx];
            row_ptr[nbase + idx] = cbase + offi;
            csr_src[cbase + offi] = nbase + idx;   // self-loop first
            cur[idx] = offi + 1;
        }
    }
    if (b == NB2 - 1 && t == 0) row_ptr[N_NODES] = cbase + ec + nn;
    __syncthreads();
    for (int i = t; i < ec; i += 256) {
        unsigned p = packed[pbase + i];
        int dl = p >> 17, s = (int)(p & 0x1FFFFu);
        int pos = atomicAdd(&cur[dl], 1);
        csr_src[cbase + pos] = s;
    }
}

// ---------------- LDS-staged coalesced GEMM, balanced tile ----------------
// C[N x 64] = A[N x K] @ W[K x 64]; 64 rows/block, 4 rows x 4 cols per thread.
// DOTS variant writes C as packed bf16 (for the agg gather) and as_/ad_ from
// fp32 accumulators. #pragma unroll 2 caps register pressure (R7 spill lesson).
#define GBR 64
#define KC  64
#define SAP (KC + 4)

template<int K, bool ACT, bool DOTS>
__global__ __launch_bounds__(256) void gemm_lds_kernel(
        const float* __restrict__ A, const float* __restrict__ W,
        const float* __restrict__ bias,
        const float* __restrict__ asrc, const float* __restrict__ adst,
        float* __restrict__ C, float* __restrict__ as_, float* __restrict__ ad_) {
    __shared__ __align__(16) float sW[KC * 64];      // 16 KB
    __shared__ __align__(16) float sA[GBR][SAP];     // 17.4 KB
    int t = threadIdx.x;
    int r0 = blockIdx.x * GBR;
    int wave = t >> 6, lane = t & 63;
    int tr = wave * 4 + (lane >> 4);     // 0..15; local rows tr + 16*i, i=0..3
    int c0 = (lane & 15) * 4;

    float acc[4][4];
    #pragma unroll
    for (int i = 0; i < 4; ++i)
        #pragma unroll
        for (int j = 0; j < 4; ++j) acc[i][j] = 0.f;

    for (int kc = 0; kc < K; kc += KC) {
        if (kc) __syncthreads();
        {
            const float4* W4 = (const float4*)(W + kc * 64);
            float4* sW4 = (float4*)sW;
            for (int i = t; i < KC * 16; i += 256) sW4[i] = W4[i];
        }
        for (int it = 0; it < (GBR * KC / 4) / 256; ++it) {
            int idx = it * 256 + t;
            int r = idx >> 4;
            int c4 = idx & 15;
            int gr = r0 + r;
            float4 v = make_float4(0.f, 0.f, 0.f, 0.f);
            if (gr < N_NODES) v = *(const float4*)&A[(size_t)gr * K + kc + c4 * 4];
            *(float4*)&sA[r][c4 * 4] = v;
        }
        __syncthreads();
        #pragma unroll 2
        for (int kk = 0; kk < KC; kk += 4) {
            float4 w0 = *(const float4*)&sW[(kk + 0) * 64 + c0];
            float4 w1 = *(const float4*)&sW[(kk + 1) * 64 + c0];
            float4 w2 = *(const float4*)&sW[(kk + 2) * 64 + c0];
            float4 w3 = *(const float4*)&sW[(kk + 3) * 64 + c0];
            #pragma unroll
            for (int i = 0; i < 4; ++i) {
                float4 a = *(const float4*)&sA[tr + 16 * i][kk];
                acc[i][0] += a.x * w0.x + a.y * w1.x + a.z * w2.x + a.w * w3.x;
                acc[i][1] += a.x * w0.y + a.y * w1.y + a.z * w2.y + a.w * w3.y;
                acc[i][2] += a.x * w0.z + a.y * w1.z + a.z * w2.z + a.w * w3.z;
                acc[i][3] += a.x * w0.w + a.y * w1.w + a.z * w2.w + a.w * w3.w;
            }
        }
    }

    float bs[4] = {0.f, 0.f, 0.f, 0.f};
    float av[4], dv[4];
    if (ACT) {
        #pragma unroll
        for (int j = 0; j < 4; ++j) bs[j] = bias[c0 + j];
    }
    if (DOTS) {
        #pragma unroll
        for (int j = 0; j < 4; ++j) { av[j] = asrc[c0 + j]; dv[j] = adst[c0 + j]; }
    }
    #pragma unroll
    for (int i = 0; i < 4; ++i) {
        int grow = r0 + tr + 16 * i;
        if (grow >= N_NODES) continue;
        if (DOTS) {
            // pack bf16x4 (8B) per thread; row = 32 uints
            unsigned p0 = (unsigned)f2bf(acc[i][0]) | ((unsigned)f2bf(acc[i][1]) << 16);
            unsigned p1 = (unsigned)f2bf(acc[i][2]) | ((unsigned)f2bf(acc[i][3]) << 16);
            *(uint2*)&((unsigned*)C)[(size_t)grow * 32 + (c0 >> 1)] = make_uint2(p0, p1);
            float ds = acc[i][0] * av[0] + acc[i][1] * av[1] + acc[i][2] * av[2] + acc[i][3] * av[3];
            float dd = acc[i][0] * dv[0] + acc[i][1] * dv[1] + acc[i][2] * dv[2] + acc[i][3] * dv[3];
            #pragma unroll
            for (int off = 1; off < 16; off <<= 1) {
                ds += __shfl_xor(ds, off);
                dd += __shfl_xor(dd, off);
            }
            if ((lane & 15) == 0) { as_[grow] = ds; ad_[grow] = dd; }
        } else {
            float4 o;
            float* op = (float*)&o;
            #pragma unroll
            for (int j = 0; j < 4; ++j) {
                float v = acc[i][j];
                if (ACT) { v += bs[j]; v = v > 0.f ? v : 0.01f * v; }
                op[j] = v;
            }
            *(float4*)&C[(size_t)grow * 64 + c0] = o;
        }
    }
}

// ---------------- fused aggregation (bf16 gather, 2 edges/wave) ----------------
// Wave = one dst node. Phase 1: 64-lane ex staging + denom. Phase 2: lanes
// split in halves; half h processes edges i+h (stride 2); each lane reads one
// bf16x2 word (row = 128 B, coalesced across 32 lanes); fp32 accumulate;
// shfl_xor(32) combine; float2 store.
__global__ __launch_bounds__(256) void agg_kernel(
        const int* __restrict__ row_ptr, const int* __restrict__ csr_src,
        const float* __restrict__ as_, const float* __restrict__ ad_,
        const unsigned* __restrict__ hw32, const float* __restrict__ bc,
        float* __restrict__ hout) {
    __shared__ float exbuf[4][MAXD];
    __shared__ int   sbuf[4][MAXD];
    int wave = threadIdx.x >> 6, lane = threadIdx.x & 63;
    int node = blockIdx.x * 4 + wave;
    if (node >= N_NODES) return;
    int rs = row_ptr[node], re = row_ptr[node + 1];
    int deg = re - rs;
    float aD = ad_[node];
    float psum = 0.f;
    for (int i = lane; i < deg; i += 64) {
        int s = csr_src[rs + i];
        float v = as_[s] + aD;
        v = v > 0.f ? v : 0.2f * v;
        float p = __expf(v);
        if (deg <= MAXD) { exbuf[wave][i] = p; sbuf[wave][i] = s; }
        psum += p;
    }
    #pragma unroll
    for (int off = 32; off >= 1; off >>= 1) psum += __shfl_xor(psum, off);
    float inv = 1.f / (psum + 1e-16f);

    int half = lane >> 5, fl = lane & 31;
    float acc0 = 0.f, acc1 = 0.f;
    if (deg <= MAXD) {
        int i = half;
        for (; i + 6 < deg; i += 8) {
            int s0 = sbuf[wave][i],     s1 = sbuf[wave][i + 2];
            int s2 = sbuf[wave][i + 4], s3 = sbuf[wave][i + 6];
            float w0 = exbuf[wave][i]     * inv, w1 = exbuf[wave][i + 2] * inv;
            float w2 = exbuf[wave][i + 4] * inv, w3 = exbuf[wave][i + 6] * inv;
            unsigned p0 = hw32[(size_t)s0 * 32 + fl];
            unsigned p1 = hw32[(size_t)s1 * 32 + fl];
            unsigned p2 = hw32[(size_t)s2 * 32 + fl];
            unsigned p3 = hw32[(size_t)s3 * 32 + fl];
            acc0 += w0 * bf_lo(p0) + w1 * bf_lo(p1) + w2 * bf_lo(p2) + w3 * bf_lo(p3);
            acc1 += w0 * bf_hi(p0) + w1 * bf_hi(p1) + w2 * bf_hi(p2) + w3 * bf_hi(p3);
        }
        for (; i < deg; i += 2) {
            float w = exbuf[wave][i] * inv;
            unsigned p = hw32[(size_t)sbuf[wave][i] * 32 + fl];
            acc0 += w * bf_lo(p);
            acc1 += w * bf_hi(p);
        }
    } else {
        for (int i = half; i < deg; i += 2) {
            int s = csr_src[rs + i];
            float v = as_[s] + aD;
            v = v > 0.f ? v : 0.2f * v;
            float w = __expf(v) * inv;
            unsigned p = hw32[(size_t)s * 32 + fl];
            acc0 += w * bf_lo(p);
            acc1 += w * bf_hi(p);
        }
    }
    acc0 += __shfl_xor(acc0, 32);
    acc1 += __shfl_xor(acc1, 32);
    if (half == 0) {
        float v0 = acc0 + bc[2 * fl];
        float v1 = acc1 + bc[2 * fl + 1];
        v0 = v0 > 0.f ? v0 : 0.01f * v0;
        v1 = v1 > 0.f ? v1 : 0.01f * v1;
        *(float2*)&hout[(size_t)node * H_DIM + 2 * fl] = make_float2(v0, v1);
    }
}

// ---------------- output GEMM + log_softmax ----------------
__global__ __launch_bounds__(256) void out_logsoftmax_kernel(
        const float* __restrict__ h, const float* __restrict__ W,
        const float* __restrict__ b, float* __restrict__ out) {
    __shared__ float sW[H_DIM * C_OUT];
    __shared__ float sh[16][H_DIM];
    __shared__ float sb[C_OUT];
    int t = threadIdx.x;
    for (int i = t; i < H_DIM * C_OUT; i += 256) sW[i] = W[i];
    if (t < C_OUT) sb[t] = b[t];
    int row0 = blockIdx.x * 16;
    for (int i = t; i < 16 * H_DIM; i += 256) {
        int r = i >> 6, k = i & 63;
        sh[r][k] = h[(row0 + r) * H_DIM + k];
    }
    __syncthreads();
    int r = t >> 4, c = t & 15;
    float acc = sb[c];
    #pragma unroll
    for (int k = 0; k < H_DIM; ++k) acc += sh[r][k] * sW[k * C_OUT + c];
    float m = acc;
    #pragma unroll
    for (int off = 8; off >= 1; off >>= 1) m = fmaxf(m, __shfl_xor(m, off, 16));
    float e = __expf(acc - m);
    float ssum = e;
    #pragma unroll
    for (int off = 8; off >= 1; off >>= 1) ssum += __shfl_xor(ssum, off, 16);
    out[(row0 + r) * C_OUT + c] = acc - m - __logf(ssum);
}

extern "C" void kernel_launch(void* const* d_in, const int* in_sizes, int n_in,
                              void* d_out, int out_size, void* d_ws, size_t ws_size,
                              hipStream_t stream) {
    const float* x     = (const float*)d_in[0];
    const void*  eidx  = d_in[1];
    const float* W_in  = (const float*)d_in[3];
    const float* b_in  = (const float*)d_in[4];
    const float* Wc    = (const float*)d_in[5];
    const float* a_src = (const float*)d_in[6];
    const float* a_dst = (const float*)d_in[7];
    const float* bc    = (const float*)d_in[8];
    const float* W_out = (const float*)d_in[9];
    const float* b_out = (const float*)d_in[10];
    float* out = (float*)d_out;

    // workspace layout (hw holds bf16 now, keep float-sized slot for simplicity)
    float* h        = (float*)d_ws;                        // N*64 f32
    float* hw       = h  + (size_t)N_NODES * H_DIM;        // N*64 (bf16 packed, uses half)
    float* as_      = hw + (size_t)N_NODES * H_DIM;        // N
    float* ad_      = as_ + N_NODES;                       // N
    int*   row_ptr  = (int*)(ad_ + N_NODES);               // N+1
    int*   csr_src  = row_ptr + N_NODES + 1;               // E+N
    unsigned int* packed = (unsigned int*)(csr_src + NTOT);// NB2*BCAP
    int*   bcur     = (int*)(packed + (size_t)NB2 * BCAP); // NB2
    int*   ebase    = bcur + NB2;                          // NB2
    int*   flag     = ebase + NB2;                         // 1

    detect64_kernel<<<1, 256, 0, stream>>>((const unsigned int*)eidx, flag);
    hipMemsetAsync(bcur, 0, NB2 * sizeof(int), stream);
    bucket_scatter2<<<PB, 256, 0, stream>>>(eidx, flag, bcur, packed);
    bucket_scan2<<<1, 256, 0, stream>>>(bcur, ebase);
    csr_build2<<<NB2, 256, 0, stream>>>(packed, bcur, ebase, row_ptr, csr_src);

    int gblocks = (N_NODES + GBR - 1) / GBR;
    gemm_lds_kernel<F_IN, true, false><<<gblocks, 256, 0, stream>>>(
        x, W_in, b_in, nullptr, nullptr, h, nullptr, nullptr);

    float* hin = h;
    float* hx  = hw;
    for (int l = 0; l < L_LAYERS; ++l) {
        gemm_lds_kernel<H_DIM, false, true><<<gblocks, 256, 0, stream>>>(
            hin, Wc + l * H_DIM * H_DIM, nullptr,
            a_src + l * H_DIM, a_dst + l * H_DIM, hx, as_, ad_);
        agg_kernel<<<(N_NODES + 3) / 4, 256, 0, stream>>>(
            row_ptr, csr_src, as_, ad_, (const unsigned*)hx, bc + l * H_DIM, hin);
    }

    out_logsoftmax_kernel<<<N_NODES / 16, 256, 0, stream>>>(hin, W_out, b_out, out);
}